// Round 3
// baseline (151.951 us; speedup 1.0000x reference)
//
#include <hip/hip_runtime.h>

#define NR 4096      // rows per batch
#define DD 512       // feature dim
#define TWO_N 8192

using bf16x8 = __attribute__((ext_vector_type(8))) short;   // 8 bf16 in 4 VGPRs (guide §3 form)
using f32x4  = __attribute__((ext_vector_type(4))) float;

__device__ __forceinline__ unsigned short f2bf(float f) {
    union { float f; unsigned u; } v; v.f = f;
    unsigned r = v.u + 0x7fff + ((v.u >> 16) & 1);   // round-to-nearest-even
    return (unsigned short)(r >> 16);
}

// Kernel 0: zero the row-sum accumulator S[8192]
__global__ __launch_bounds__(256) void ntx_zero_kernel(float* __restrict__ S) {
    const int i = blockIdx.x * 256 + threadIdx.x;
    if (i < TWO_N) S[i] = 0.f;
}

// Kernel 1: L2-normalize rows of A and B -> bf16 X = [nA; nB], plus fp32 d12[i] = nA_i . nB_i
__global__ __launch_bounds__(256) void ntx_nrm_kernel(const float* __restrict__ A,
                                                      const float* __restrict__ B,
                                                      unsigned short* __restrict__ X,
                                                      float* __restrict__ d12) {
    const int row = blockIdx.x;
    const int t = threadIdx.x;            // 256 threads, 2 elems each
    const int lane = t & 63, wid = t >> 6;

    const float2 av = *(const float2*)(A + row * DD + 2 * t);
    const float2 bv = *(const float2*)(B + row * DD + 2 * t);
    float sa = av.x * av.x + av.y * av.y;
    float sb = bv.x * bv.x + bv.y * bv.y;
#pragma unroll
    for (int o = 32; o; o >>= 1) { sa += __shfl_down(sa, o); sb += __shfl_down(sb, o); }

    __shared__ float red[12];
    if (lane == 0) { red[wid] = sa; red[4 + wid] = sb; }
    __syncthreads();
    const float ta = red[0] + red[1] + red[2] + red[3];
    const float tb = red[4] + red[5] + red[6] + red[7];
    const float ra = 1.f / fmaxf(sqrtf(ta), 1e-8f);
    const float rb = 1.f / fmaxf(sqrtf(tb), 1e-8f);
    const float nax = av.x * ra, nay = av.y * ra;
    const float nbx = bv.x * rb, nby = bv.y * rb;

    *(unsigned*)(X + row * DD + 2 * t) =
        (unsigned)f2bf(nax) | ((unsigned)f2bf(nay) << 16);
    *(unsigned*)(X + (NR + row) * DD + 2 * t) =
        (unsigned)f2bf(nbx) | ((unsigned)f2bf(nby) << 16);

    float dt = nax * nbx + nay * nby;
#pragma unroll
    for (int o = 32; o; o >>= 1) dt += __shfl_down(dt, o);
    if (lane == 0) red[8 + wid] = dt;
    __syncthreads();
    if (t == 0) d12[row] = red[8] + red[9] + red[10] + red[11];
}

// Kernel 2: logits[r,c] = 2 * X_r . Z_c with Z_c = X_{c^4096}; masked exp row-sums -> S[r]
// 128x128 tile, 4 waves (2x2), each wave 64x64 via 4x4 frags of mfma_f32_16x16x32_bf16.
__global__ __launch_bounds__(256) void ntx_gemm_lse_kernel(const unsigned short* __restrict__ X,
                                                           float* __restrict__ S) {
    __shared__ unsigned short As[128][32];
    __shared__ unsigned short Bs[128][32];

    const int t = threadIdx.x;
    const int lane = t & 63, wid = t >> 6;
    const int waveRow = wid >> 1, waveCol = wid & 1;
    const int lr = lane & 15, grp = lane >> 4;
    const int ko = grp * 8;
    const int rowTile = blockIdx.y * 128, colTile = blockIdx.x * 128;

    f32x4 acc[4][4] = {};

    const int sr = t >> 2;          // 0..63
    const int sc = (t & 3) * 8;     // 0,8,16,24

    for (int kt = 0; kt < DD; kt += 32) {
        __syncthreads();
#pragma unroll
        for (int q = 0; q < 2; ++q) {
            const int r = q * 64 + sr;
            *(int4*)&As[r][sc] = *(const int4*)(X + (size_t)(rowTile + r) * DD + kt + sc);
            *(int4*)&Bs[r][sc] = *(const int4*)(X + (size_t)((colTile + r) ^ NR) * DD + kt + sc);
        }
        __syncthreads();

        bf16x8 af[4], bfr[4];
#pragma unroll
        for (int m = 0; m < 4; ++m)
            af[m] = *(const bf16x8*)&As[waveRow * 64 + m * 16 + lr][ko];
#pragma unroll
        for (int n = 0; n < 4; ++n)
            bfr[n] = *(const bf16x8*)&Bs[waveCol * 64 + n * 16 + lr][ko];
#pragma unroll
        for (int m = 0; m < 4; ++m)
#pragma unroll
            for (int n = 0; n < 4; ++n)
                acc[m][n] = __builtin_amdgcn_mfma_f32_16x16x32_bf16(af[m], bfr[n], acc[m][n], 0, 0, 0);
    }

    // Epilogue: C/D layout col = lane&15, row = (lane>>4)*4 + reg  (guide §3, m89/m91-verified)
#pragma unroll
    for (int m = 0; m < 4; ++m) {
#pragma unroll
        for (int reg = 0; reg < 4; ++reg) {
            const int R = rowTile + waveRow * 64 + m * 16 + grp * 4 + reg;
            const int maskC = (R + NR) & (TWO_N - 1);
            float rs = 0.f;
#pragma unroll
            for (int n = 0; n < 4; ++n) {
                const int C = colTile + waveCol * 64 + n * 16 + lr;
                const float v = acc[m][n][reg] * 2.0f;   // inv temperature
                rs += (C == maskC) ? 0.f : __expf(v);
            }
            rs += __shfl_xor(rs, 1);
            rs += __shfl_xor(rs, 2);
            rs += __shfl_xor(rs, 4);
            rs += __shfl_xor(rs, 8);
            if (lr == 0) atomicAdd(&S[R], rs);
        }
    }
}

// Kernel 3: loss = mean_r( log(S[r]) - 2*d12[r mod N] ), written as FLOAT32 scalar.
__global__ __launch_bounds__(256) void ntx_loss_kernel(const float* __restrict__ S,
                                                       const float* __restrict__ d12,
                                                       float* __restrict__ out) {
    const int t = threadIdx.x;
    float a = 0.f;
    for (int r = t; r < TWO_N; r += 256)
        a += __logf(S[r]) - 2.0f * d12[r & (NR - 1)];
    const int lane = t & 63, wid = t >> 6;
#pragma unroll
    for (int o = 32; o; o >>= 1) a += __shfl_down(a, o);
    __shared__ float red[4];
    if (lane == 0) red[wid] = a;
    __syncthreads();
    if (t == 0) out[0] = (red[0] + red[1] + red[2] + red[3]) * (1.f / (float)TWO_N);
}

extern "C" void kernel_launch(void* const* d_in, const int* in_sizes, int n_in,
                              void* d_out, int out_size, void* d_ws, size_t ws_size,
                              hipStream_t stream) {
    const float* A = (const float*)d_in[0];
    const float* B = (const float*)d_in[1];

    // workspace layout
    unsigned short* X = (unsigned short*)d_ws;                    // 8192*512*2 = 8 MB
    float* S   = (float*)((char*)d_ws + (size_t)TWO_N * DD * 2);  // 32 KB
    float* d12 = (float*)((char*)S + (size_t)TWO_N * 4);          // 16 KB

    ntx_zero_kernel<<<TWO_N / 256, 256, 0, stream>>>(S);

    ntx_nrm_kernel<<<NR, 256, 0, stream>>>(A, B, X, d12);

    dim3 grid(TWO_N / 128, TWO_N / 128);
    ntx_gemm_lse_kernel<<<grid, 256, 0, stream>>>(X, S);

    ntx_loss_kernel<<<1, 256, 0, stream>>>(S, d12, (float*)d_out);
}